// Round 10
// baseline (517.854 us; speedup 1.0000x reference)
//
#include <hip/hip_runtime.h>
#include <hip/hip_bf16.h>
#include <math.h>

// MoE top-2, E=8, D=1024, F=2048, N=8192 tokens.
// R6/R7: single barrier per K-step; router emits xb. 789->769.
// R8: 8-wave 512-thr gemm blocks. 769->726.
// R9: aux atomic fix (LDS histograms + padded counter lines). 726->500.
// R10/R12: 3 blocks/CU attempt -- occupancy DID NOT move (43%), time flat.
//      TLP lever exhausted; invariant is ~1600-cycle K-step wall vs ~155
//      cycles of MFMA work (fixed barrier/wait/latency overhead per step).
// R13: BK 32 -> 64. Amortize the fixed per-K-step cost over 2x MFMA:
//      16 MFMA + 12 ds_read + 4 gload_lds per wave per step; K-steps halve
//      (gemm1 16, gemm2 32). LDS [2 buf][128][64] = 64KB/block -> still
//      2 blocks/CU. Ledger (depth-1, 2 buf): prologue stages tile0; iter kt:
//      vmcnt(0) [tile kt landed, issued 1 step (~2500cy) ago], barrier
//      [all waves' loads landed; buf^1 reads completed -- MFMA(kt-1) forced
//      lgkm drain before barrier], prefetch kt+1 -> buf^1, compute cb.
//      New swizzle for 128B rows (exact bank wrap): store chunk c of row r
//      at c^(r&7); staging scol=((l&7)^((l>>3)&7)); read (ks*4+lg)^(lc&7).
//      Wave read = 8 accesses/bank = theoretical minimum.

#define E_ 8
#define D_ 1024
#define F_ 2048
#define N_ 8192
#define MAX_MTILES 136                 // ceil((N*K + E*127)/128)
#define MAX_SLOTS (MAX_MTILES * 128)   // 17408
#define RT_TPB 16                      // router tokens per block

typedef __attribute__((ext_vector_type(8))) short short8;
typedef __attribute__((ext_vector_type(4))) float f32x4;
typedef unsigned short u16;

__device__ __forceinline__ u16 f2bf(float f) {
  unsigned int u = __float_as_uint(f);
  unsigned int r = (u + 0x7fffu + ((u >> 16) & 1u)) >> 16;  // RNE
  return (u16)r;
}

__device__ __forceinline__ void gload_lds16(const void* g, void* lds) {
  __builtin_amdgcn_global_load_lds(
      (const __attribute__((address_space(1))) unsigned int*)g,
      (__attribute__((address_space(3))) unsigned int*)lds,
      16, 0, 0);
}

__device__ __forceinline__ void raw_barrier() {
  asm volatile("s_barrier" ::: "memory");
}
__device__ __forceinline__ void wait_vmcnt0() {
  asm volatile("s_waitcnt vmcnt(0)" ::: "memory");
}

// ---------------- router: wave per token, 16 tokens/block ----------------
__global__ __launch_bounds__(256) void router_kernel(
    const float* __restrict__ x, const float* __restrict__ Wr,
    int* __restrict__ texp, float* __restrict__ tgate, int* __restrict__ counts,
    u16* __restrict__ xb) {
  __shared__ int lcnt[E_];
  if (threadIdx.x < E_) lcnt[threadIdx.x] = 0;
  __syncthreads();
  const int wid = threadIdx.x >> 6;
  const int lane = threadIdx.x & 63;
#pragma unroll
  for (int it = 0; it < RT_TPB / 4; ++it) {
    const int token = blockIdx.x * RT_TPB + it * 4 + wid;
    const float4* xr = (const float4*)(x + (size_t)token * D_);
    ushort4* xbr = (ushort4*)(xb + (size_t)token * D_);
    float acc[E_];
#pragma unroll
    for (int e = 0; e < E_; ++e) acc[e] = 0.f;
#pragma unroll
    for (int c = 0; c < 4; ++c) {
      const int c4 = c * 64 + lane;
      const float4 xv = xr[c4];
      ushort4 o;
      o.x = f2bf(xv.x); o.y = f2bf(xv.y); o.z = f2bf(xv.z); o.w = f2bf(xv.w);
      xbr[c4] = o;
#pragma unroll
      for (int e = 0; e < E_; ++e) {
        const float4 wv = ((const float4*)(Wr + e * D_))[c4];
        acc[e] += xv.x * wv.x + xv.y * wv.y + xv.z * wv.z + xv.w * wv.w;
      }
    }
#pragma unroll
    for (int e = 0; e < E_; ++e)
#pragma unroll
      for (int s = 32; s > 0; s >>= 1) acc[e] += __shfl_xor(acc[e], s, 64);
    if (lane == 0) {
      int e0 = 0;
#pragma unroll
      for (int e = 1; e < E_; ++e) if (acc[e] > acc[e0]) e0 = e;
      int e1 = (e0 == 0) ? 1 : 0;
#pragma unroll
      for (int e = 0; e < E_; ++e) if (e != e0 && acc[e] > acc[e1]) e1 = e;
      const float g0 = 1.f / (1.f + __expf(acc[e1] - acc[e0]));
      texp[2 * token] = e0; texp[2 * token + 1] = e1;
      tgate[2 * token] = g0; tgate[2 * token + 1] = 1.f - g0;
      atomicAdd(&lcnt[e0], 1);
      atomicAdd(&lcnt[e1], 1);
    }
  }
  __syncthreads();
  if (threadIdx.x < E_)
    atomicAdd(&counts[threadIdx.x * 32], lcnt[threadIdx.x]);  // padded lines
}

// offsets (1 thread) + slot init, one launch
__global__ void meta_kernel(const int* __restrict__ counts,
                            int* __restrict__ off, int* __restrict__ cursors,
                            int* __restrict__ tok, float* __restrict__ gate) {
  const int s = blockIdx.x * 256 + threadIdx.x;
  tok[s] = 0;
  gate[s] = 0.f;
  if (blockIdx.x == 0 && threadIdx.x == 0) {
    int o = 0;
    for (int e = 0; e < E_; ++e) {
      off[e] = o; cursors[e * 32] = o;
      o += (counts[e * 32] + 127) & ~127;
    }
    off[E_] = o;
  }
}

// place: per-block two-pass LDS reservation; 8 padded global atomics/block.
__global__ __launch_bounds__(256) void place_kernel(
    const int* __restrict__ texp, const float* __restrict__ tgate,
    int* __restrict__ cursors, int* __restrict__ tok,
    float* __restrict__ gate) {
  __shared__ int cnt[E_], basee[E_], rk[E_];
  const int t = threadIdx.x;
  if (t < E_) { cnt[t] = 0; rk[t] = 0; }
  __syncthreads();
  const int n = blockIdx.x * 256 + t;
  const int e0 = texp[2 * n], e1 = texp[2 * n + 1];
  atomicAdd(&cnt[e0], 1);
  atomicAdd(&cnt[e1], 1);
  __syncthreads();
  if (t < E_) basee[t] = atomicAdd(&cursors[t * 32], cnt[t]);
  __syncthreads();
  {
    const int r = atomicAdd(&rk[e0], 1);
    const int p = basee[e0] + r;
    tok[p] = n; gate[p] = tgate[2 * n];
  }
  {
    const int r = atomicAdd(&rk[e1], 1);
    const int p = basee[e1] + r;
    tok[p] = n; gate[p] = tgate[2 * n + 1];
  }
}

// in[e][r][c] (fp32) -> out[e][c][r] (bf16); 64x64 tiles, coalesced both sides.
__global__ __launch_bounds__(256) void transpose_cast_kernel(
    const float* __restrict__ in, u16* __restrict__ out, int R, int C) {
  __shared__ float tile[64][65];
  const int e = blockIdx.z;
  const int c0 = blockIdx.x * 64, r0 = blockIdx.y * 64;
  const float* src = in + (size_t)e * R * C;
  u16* dst = out + (size_t)e * R * C;
  const int t = threadIdx.x;
  const int rr = t >> 4;        // 0..15
  const int cc = t & 15;        // 0..15
#pragma unroll
  for (int p = 0; p < 4; ++p) {
    const int r = rr + p * 16;
    const float4 v = *(const float4*)&src[(size_t)(r0 + r) * C + c0 + cc * 4];
    tile[r][cc * 4 + 0] = v.x; tile[r][cc * 4 + 1] = v.y;
    tile[r][cc * 4 + 2] = v.z; tile[r][cc * 4 + 3] = v.w;
  }
  __syncthreads();
#pragma unroll
  for (int p = 0; p < 4; ++p) {
    const int c = rr + p * 16;       // dst row = source col
    const int j = cc * 4;
    ushort4 o;
    o.x = f2bf(tile[j + 0][c]);
    o.y = f2bf(tile[j + 1][c]);
    o.z = f2bf(tile[j + 2][c]);
    o.w = f2bf(tile[j + 3][c]);
    *(ushort4*)&dst[(size_t)(c0 + c) * R + r0 + j] = o;
  }
}

// -- grouped GEMMs: 128x128 tile, BK=64, 2-buf depth-1, 1 barrier/K, 8 waves -
// LDS per operand: [2 buf][128 rows][64 k] u16 (16KB/buf). Staging: wave w
// owns rows w*16..+15; call j covers rows w*16+j*8+(l>>3), lane l writes
// phys chunk (l&7); source chunk = (l&7)^((l>>3)&7) (inverse swizzle).
// Read: row ..+lc, slice ks, logical chunk ks*4+lg, phys = ^(lc&7).

// GEMM1: h[slot,f] = gelu( sum_d xb[tok[slot],d] * W1t[e][f,d] + b1[e][f] )
__global__ __launch_bounds__(512, 4) void gemm1_kernel(
    const u16* __restrict__ xb, const u16* __restrict__ w1t,
    const float* __restrict__ b1, const int* __restrict__ tok,
    const int* __restrict__ off, u16* __restrict__ h) {
  __shared__ __align__(16) u16 As[2 * 8192];
  __shared__ __align__(16) u16 Bs[2 * 8192];
  const int b = blockIdx.x;
  const int xcd = b & 7;
  const int local = b >> 3;            // 0..271
  const int tn = local & 15;           // 16 N-tiles (F/128)
  const int tm = xcd * 17 + (local >> 4);
  const int base = tm * 128;
  if (base >= off[E_]) return;
  int e = 0;
#pragma unroll
  for (int i = 1; i < E_; ++i) if (base >= off[i]) e = i;

  const int t = threadIdx.x;
  const int w = t >> 6, l = t & 63;
  // staging source
  const int sr = l >> 3;                       // 0..7 within 8-row group
  const int scol = ((l & 7) ^ sr) * 8;         // swizzled 16B chunk (u16)
  const int rA0 = w * 16 + sr;
  const u16* gA0 = xb + (size_t)tok[base + rA0] * D_ + scol;
  const u16* gA1 = xb + (size_t)tok[base + rA0 + 8] * D_ + scol;
  const u16* gB0 = w1t + ((size_t)e * F_ + tn * 128 + rA0) * D_ + scol;
  const u16* gB1 = w1t + ((size_t)e * F_ + tn * 128 + rA0 + 8) * D_ + scol;
  // compute-side ids: 2 M-waves x 4 N-waves; per-wave 64x32 output
  const int wm = w >> 2, wn = w & 3;
  const int lc = l & 15, lg = l >> 4;

  f32x4 acc[4][2];
#pragma unroll
  for (int i = 0; i < 4; ++i)
#pragma unroll
    for (int j = 0; j < 2; ++j) acc[i][j] = (f32x4)(0.f);

  // prologue: tile 0 -> buf0
  gload_lds16(gA0, &As[w * 1024]);
  gload_lds16(gA1, &As[w * 1024 + 512]);
  gload_lds16(gB0, &Bs[w * 1024]);
  gload_lds16(gB1, &Bs[w * 1024 + 512]);

  const int KT = D_ / 64;  // 16
  int cb = 0;
  for (int kt = 0; kt < KT; ++kt) {
    wait_vmcnt0();   // tile kt landed (issued 1 K-step ago)
    raw_barrier();   // all waves' loads landed; buf^1 reads completed
    const int nb = cb ^ 1;
    const int k0 = ((kt + 1 < KT) ? kt + 1 : kt) * 64;  // tail clamp
    gload_lds16(gA0 + k0, &As[nb * 8192 + w * 1024]);
    gload_lds16(gA1 + k0, &As[nb * 8192 + w * 1024 + 512]);
    gload_lds16(gB0 + k0, &Bs[nb * 8192 + w * 1024]);
    gload_lds16(gB1 + k0, &Bs[nb * 8192 + w * 1024 + 512]);
#pragma unroll
    for (int ks = 0; ks < 2; ++ks) {
      const int pc = ((ks * 4 + lg) ^ (lc & 7)) * 8;   // phys chunk offset
      short8 a[4], bb[2];
#pragma unroll
      for (int mi = 0; mi < 4; ++mi)
        a[mi] = *(const short8*)&As[cb * 8192 + (wm * 64 + mi * 16 + lc) * 64 + pc];
#pragma unroll
      for (int ni = 0; ni < 2; ++ni)
        bb[ni] = *(const short8*)&Bs[cb * 8192 + (wn * 32 + ni * 16 + lc) * 64 + pc];
#pragma unroll
      for (int mi = 0; mi < 4; ++mi)
#pragma unroll
        for (int ni = 0; ni < 2; ++ni)
          acc[mi][ni] = __builtin_amdgcn_mfma_f32_16x16x32_bf16(a[mi], bb[ni], acc[mi][ni], 0, 0, 0);
    }
    cb ^= 1;
  }
#pragma unroll
  for (int ni = 0; ni < 2; ++ni) {
    const int gcol = tn * 128 + wn * 32 + ni * 16 + lc;
    const float bias = b1[e * F_ + gcol];
#pragma unroll
    for (int mi = 0; mi < 4; ++mi)
#pragma unroll
      for (int r = 0; r < 4; ++r) {
        const int slot = base + wm * 64 + mi * 16 + lg * 4 + r;
        const float v = acc[mi][ni][r] + bias;
        const float g = 0.5f * v * (1.f + erff(v * 0.70710678118654752f));
        h[(size_t)slot * F_ + gcol] = f2bf(g);
      }
  }
}

// GEMM2: out[tok[slot],d] += gate[slot] * ( sum_f h[slot,f]*W2t[e][d,f] + b2[e][d] )
__global__ __launch_bounds__(512, 4) void gemm2_kernel(
    const u16* __restrict__ h, const u16* __restrict__ w2t,
    const float* __restrict__ b2, const int* __restrict__ tok,
    const float* __restrict__ gate, const int* __restrict__ off,
    float* __restrict__ out) {
  __shared__ __align__(16) u16 As[2 * 8192];
  __shared__ __align__(16) u16 Bs[2 * 8192];
  const int b = blockIdx.x;
  const int xcd = b & 7;
  const int local = b >> 3;            // 0..135
  const int tn = local & 7;            // 8 N-tiles (D/128)
  const int tm = xcd * 17 + (local >> 3);
  const int base = tm * 128;
  if (base >= off[E_]) return;
  int e = 0;
#pragma unroll
  for (int i = 1; i < E_; ++i) if (base >= off[i]) e = i;

  const int t = threadIdx.x;
  const int w = t >> 6, l = t & 63;
  const int sr = l >> 3;
  const int scol = ((l & 7) ^ sr) * 8;
  const int rA0 = w * 16 + sr;
  const u16* gA0 = h + (size_t)(base + rA0) * F_ + scol;
  const u16* gA1 = h + (size_t)(base + rA0 + 8) * F_ + scol;
  const u16* gB0 = w2t + ((size_t)e * D_ + tn * 128 + rA0) * F_ + scol;
  const u16* gB1 = w2t + ((size_t)e * D_ + tn * 128 + rA0 + 8) * F_ + scol;
  const int wm = w >> 2, wn = w & 3;
  const int lc = l & 15, lg = l >> 4;

  f32x4 acc[4][2];
#pragma unroll
  for (int i = 0; i < 4; ++i)
#pragma unroll
    for (int j = 0; j < 2; ++j) acc[i][j] = (f32x4)(0.f);

  gload_lds16(gA0, &As[w * 1024]);
  gload_lds16(gA1, &As[w * 1024 + 512]);
  gload_lds16(gB0, &Bs[w * 1024]);
  gload_lds16(gB1, &Bs[w * 1024 + 512]);

  const int KT = F_ / 64;  // 32
  int cb = 0;
  for (int kt = 0; kt < KT; ++kt) {
    wait_vmcnt0();
    raw_barrier();
    const int nb = cb ^ 1;
    const int k0 = ((kt + 1 < KT) ? kt + 1 : kt) * 64;
    gload_lds16(gA0 + k0, &As[nb * 8192 + w * 1024]);
    gload_lds16(gA1 + k0, &As[nb * 8192 + w * 1024 + 512]);
    gload_lds16(gB0 + k0, &Bs[nb * 8192 + w * 1024]);
    gload_lds16(gB1 + k0, &Bs[nb * 8192 + w * 1024 + 512]);
#pragma unroll
    for (int ks = 0; ks < 2; ++ks) {
      const int pc = ((ks * 4 + lg) ^ (lc & 7)) * 8;
      short8 a[4], bb[2];
#pragma unroll
      for (int mi = 0; mi < 4; ++mi)
        a[mi] = *(const short8*)&As[cb * 8192 + (wm * 64 + mi * 16 + lc) * 64 + pc];
#pragma unroll
      for (int ni = 0; ni < 2; ++ni)
        bb[ni] = *(const short8*)&Bs[cb * 8192 + (wn * 32 + ni * 16 + lc) * 64 + pc];
#pragma unroll
      for (int mi = 0; mi < 4; ++mi)
#pragma unroll
        for (int ni = 0; ni < 2; ++ni)
          acc[mi][ni] = __builtin_amdgcn_mfma_f32_16x16x32_bf16(a[mi], bb[ni], acc[mi][ni], 0, 0, 0);
    }
    cb ^= 1;
  }
#pragma unroll
  for (int ni = 0; ni < 2; ++ni) {
    const int gcol = tn * 128 + wn * 32 + ni * 16 + lc;
    const float bias = b2[e * D_ + gcol];
#pragma unroll
    for (int mi = 0; mi < 4; ++mi)
#pragma unroll
      for (int r = 0; r < 4; ++r) {
        const int slot = base + wm * 64 + mi * 16 + lg * 4 + r;
        const float gt = gate[slot];
        const int tk = tok[slot];
        const float v = gt * (acc[mi][ni][r] + bias);
        unsafeAtomicAdd(&out[(size_t)tk * D_ + gcol], v);
      }
  }
}

// ---------------- launch ----------------
extern "C" void kernel_launch(void* const* d_in, const int* in_sizes, int n_in,
                              void* d_out, int out_size, void* d_ws, size_t ws_size,
                              hipStream_t stream) {
  const float* x  = (const float*)d_in[0];
  const float* Wr = (const float*)d_in[1];
  const float* W1 = (const float*)d_in[2];
  const float* b1 = (const float*)d_in[3];
  const float* W2 = (const float*)d_in[4];
  const float* b2 = (const float*)d_in[5];
  float* out = (float*)d_out;

  char* p = (char*)d_ws;
  u16* xb  = (u16*)p;  p += (size_t)N_ * D_ * 2;
  u16* w1t = (u16*)p;  p += (size_t)E_ * D_ * F_ * 2;
  u16* w2t = (u16*)p;  p += (size_t)E_ * D_ * F_ * 2;
  u16* h   = (u16*)p;  p += (size_t)MAX_SLOTS * F_ * 2;
  int*   texp  = (int*)p;   p += (size_t)N_ * 2 * 4;
  float* tgate = (float*)p; p += (size_t)N_ * 2 * 4;
  int*   tok   = (int*)p;   p += (size_t)MAX_SLOTS * 4;
  float* gate  = (float*)p; p += (size_t)MAX_SLOTS * 4;
  int* counts  = (int*)p;          // E_*32 ints (one 128B line per expert)
  int* off     = counts + E_ * 32; // E_+1 ints
  int* cursors = off + 16;         // E_*32 ints (padded lines)

  hipMemsetAsync(counts, 0, (E_ * 32 + 16 + E_ * 32) * sizeof(int), stream);
  hipMemsetAsync(out, 0, (size_t)out_size * sizeof(float), stream);

  router_kernel<<<N_ / RT_TPB, 256, 0, stream>>>(x, Wr, texp, tgate, counts, xb);
  meta_kernel<<<MAX_SLOTS / 256, 256, 0, stream>>>(counts, off, cursors, tok, gate);
  place_kernel<<<N_ / 256, 256, 0, stream>>>(texp, tgate, cursors, tok, gate);

  transpose_cast_kernel<<<dim3(F_ / 64, D_ / 64, E_), 256, 0, stream>>>(W1, w1t, D_, F_);
  transpose_cast_kernel<<<dim3(D_ / 64, F_ / 64, E_), 256, 0, stream>>>(W2, w2t, F_, D_);

  gemm1_kernel<<<dim3(16 * MAX_MTILES), 512, 0, stream>>>(xb, w1t, b1, tok, off, h);
  gemm2_kernel<<<dim3(8 * MAX_MTILES), 512, 0, stream>>>(h, w2t, b2, tok, gate, off, out);
}